// Round 1
// baseline (604.212 us; speedup 1.0000x reference)
//
#include <hip/hip_runtime.h>

#define BATCH 25
#define LSEQ  11
#define OUTR  4
#define DIM   2048
#define VOCAB 32000
#define KSEL  1024

#define KPB   64   // k-indices per block
#define KPW   16   // k-indices per wave (4 waves/block)

__global__ __launch_bounds__(256) void ehead_kernel(
    const float* __restrict__ h,
    const float* __restrict__ wt,
    const int*   __restrict__ index,
    float*       __restrict__ out)
{
    const int nkc = KSEL / KPB;           // 16 k-chunks per (b,l)
    const int bl  = blockIdx.x / nkc;     // 0..274
    const int kc  = blockIdx.x % nkc;
    const int kbase = kc * KPB;

    __shared__ float hs[OUTR * DIM];      // 32 KiB: h[b,l,:,:]

    const float* hp = h + (size_t)bl * (OUTR * DIM);
    const int tid = threadIdx.x;

    // Stage h[b,l] into LDS: 8192 floats, 256 threads x float4 x 8 iters.
#pragma unroll
    for (int i = 0; i < (OUTR * DIM) / (256 * 4); ++i) {
        const int e = (i * 256 + tid) * 4;
        *(float4*)&hs[e] = *(const float4*)&hp[e];
    }
    __syncthreads();

    const int wave = tid >> 6;
    const int lane = tid & 63;

    const int*  ip = index + (size_t)bl * KSEL + kbase + wave * KPW;
    float*      op = out   + (size_t)bl * (OUTR * KSEL) + kbase + wave * KPW;

    for (int g = 0; g < KPW; g += 4) {
        const int i0 = ip[g + 0];
        const int i1 = ip[g + 1];
        const int i2 = ip[g + 2];
        const int i3 = ip[g + 3];
        const float4* r0 = (const float4*)(wt + (size_t)i0 * DIM);
        const float4* r1 = (const float4*)(wt + (size_t)i1 * DIM);
        const float4* r2 = (const float4*)(wt + (size_t)i2 * DIM);
        const float4* r3 = (const float4*)(wt + (size_t)i3 * DIM);

        float acc[OUTR][4];
#pragma unroll
        for (int o = 0; o < OUTR; ++o)
#pragma unroll
            for (int kk = 0; kk < 4; ++kk) acc[o][kk] = 0.f;

#pragma unroll
        for (int c = 0; c < DIM / 256; ++c) {     // 8 chunks of 256 floats
            const int off = c * 64 + lane;        // float4 index within row
            const float4 w0 = r0[off];
            const float4 w1 = r1[off];
            const float4 w2 = r2[off];
            const float4 w3 = r3[off];
#pragma unroll
            for (int o = 0; o < OUTR; ++o) {
                const float4 hv = *(const float4*)&hs[o * DIM + off * 4];
                acc[o][0] += hv.x * w0.x + hv.y * w0.y + hv.z * w0.z + hv.w * w0.w;
                acc[o][1] += hv.x * w1.x + hv.y * w1.y + hv.z * w1.z + hv.w * w1.w;
                acc[o][2] += hv.x * w2.x + hv.y * w2.y + hv.z * w2.z + hv.w * w2.w;
                acc[o][3] += hv.x * w3.x + hv.y * w3.y + hv.z * w3.z + hv.w * w3.w;
            }
        }

        // Full 64-lane butterfly reduce for each of the 16 accumulators.
#pragma unroll
        for (int o = 0; o < OUTR; ++o)
#pragma unroll
            for (int kk = 0; kk < 4; ++kk) {
                float v = acc[o][kk];
#pragma unroll
                for (int s = 32; s >= 1; s >>= 1) v += __shfl_xor(v, s, 64);
                acc[o][kk] = v;
            }

        // Lanes 0..15 each write one (o,kk) result.
        if (lane < 16) {
            float v = 0.f;
#pragma unroll
            for (int oo = 0; oo < OUTR; ++oo)
#pragma unroll
                for (int qq = 0; qq < 4; ++qq)
                    v = (oo * 4 + qq == lane) ? acc[oo][qq] : v;
            const int o  = lane >> 2;
            const int kk = lane & 3;
            op[o * KSEL + g + kk] = v;
        }
    }
}

extern "C" void kernel_launch(void* const* d_in, const int* in_sizes, int n_in,
                              void* d_out, int out_size, void* d_ws, size_t ws_size,
                              hipStream_t stream) {
    const float* h   = (const float*)d_in[0];
    const float* wt  = (const float*)d_in[1];
    const int*   idx = (const int*)d_in[2];
    float*       out = (float*)d_out;

    const int grid = BATCH * LSEQ * (KSEL / KPB);   // 4400 blocks
    ehead_kernel<<<grid, 256, 0, stream>>>(h, wt, idx, out);
}

// Round 2
// 551.084 us; speedup vs baseline: 1.0964x; 1.0964x over previous
//
#include <hip/hip_runtime.h>

#define BATCH 25
#define LSEQ  11
#define OUTR  4
#define DIM   2048
#define VOCAB 32000
#define KSEL  1024

// ---- bf16-table gather config ----
#define KPB   128              // k per block
#define KPW   32               // k per wave (4 waves/block)
#define NKC   (KSEL / KPB)     // 8 k-chunks per (b,l)
#define WBF_BYTES ((size_t)VOCAB * DIM * 2)

// ---------------- W fp32 -> bf16 (RNE) conversion ----------------
__global__ __launch_bounds__(256) void conv_kernel(const float* __restrict__ w,
                                                   ushort* __restrict__ wbf) {
    const size_t i = ((size_t)blockIdx.x * 256 + threadIdx.x) * 8;
    const float4 a = *(const float4*)(w + i);
    const float4 b = *(const float4*)(w + i + 4);
    uint4 o;
    auto cvt2 = [](float lo, float hi) -> unsigned int {
        unsigned int ul = __float_as_uint(lo), uh = __float_as_uint(hi);
        ul = (ul + 0x7FFFu + ((ul >> 16) & 1u)) >> 16;   // RNE
        uh = (uh + 0x7FFFu + ((uh >> 16) & 1u)) >> 16;
        return ul | (uh << 16);
    };
    o.x = cvt2(a.x, a.y); o.y = cvt2(a.z, a.w);
    o.z = cvt2(b.x, b.y); o.w = cvt2(b.z, b.w);
    *(uint4*)(wbf + i) = o;
}

// ---------------- gather-dot on bf16 table, h in registers ----------------
__global__ __launch_bounds__(256, 2) void gather_bf16_kernel(
    const float*  __restrict__ h,
    const ushort* __restrict__ wbf,
    const int*    __restrict__ index,
    float*        __restrict__ out)
{
    const int bl    = blockIdx.x / NKC;
    const int kc    = blockIdx.x % NKC;
    const int kbase = kc * KPB;
    const int tid   = threadIdx.x;
    const int wave  = tid >> 6;
    const int lane  = tid & 63;

    // h[bl] held in registers: lane owns elements c*512 + lane*8 + (0..7)
    // for each o, c.  128 floats/lane.
    float4 hreg[OUTR][4][2];
    const float* hp = h + (size_t)bl * (OUTR * DIM);
#pragma unroll
    for (int o = 0; o < OUTR; ++o)
#pragma unroll
        for (int c = 0; c < 4; ++c) {
            const float* p = hp + o * DIM + c * 512 + lane * 8;
            hreg[o][c][0] = *(const float4*)p;
            hreg[o][c][1] = *(const float4*)(p + 4);
        }

    const int* ip = index + (size_t)bl * KSEL + kbase + wave * KPW;
    float*     op = out   + (size_t)bl * (OUTR * KSEL) + kbase + wave * KPW;

    for (int g = 0; g < KPW; g += 4) {
        // issue all 16 row-chunk loads (4 rows x 4 chunks x 16B/lane)
        uint4 wv[4][4];
#pragma unroll
        for (int r = 0; r < 4; ++r) {
            const uint4* rp = (const uint4*)(wbf + (size_t)ip[g + r] * DIM);
#pragma unroll
            for (int c = 0; c < 4; ++c) wv[r][c] = rp[c * 64 + lane];
        }

        float acc[OUTR][4];
#pragma unroll
        for (int o = 0; o < OUTR; ++o)
#pragma unroll
            for (int r = 0; r < 4; ++r) acc[o][r] = 0.f;

#pragma unroll
        for (int r = 0; r < 4; ++r)
#pragma unroll
            for (int c = 0; c < 4; ++c) {
                const unsigned int* wd = (const unsigned int*)&wv[r][c];
#pragma unroll
                for (int m = 0; m < 4; ++m) {
                    const float flo = __uint_as_float(wd[m] << 16);
                    const float fhi = __uint_as_float(wd[m] & 0xFFFF0000u);
#pragma unroll
                    for (int o = 0; o < OUTR; ++o) {
                        const float* hh = (const float*)&hreg[o][c][0];
                        acc[o][r] += flo * hh[2 * m] + fhi * hh[2 * m + 1];
                    }
                }
            }

        // 64-lane butterfly reduce all 16 accumulators
#pragma unroll
        for (int o = 0; o < OUTR; ++o)
#pragma unroll
            for (int r = 0; r < 4; ++r) {
                float v = acc[o][r];
#pragma unroll
                for (int s = 32; s >= 1; s >>= 1) v += __shfl_xor(v, s, 64);
                acc[o][r] = v;
            }

        if (lane < 16) {
            float v = 0.f;
#pragma unroll
            for (int oo = 0; oo < OUTR; ++oo)
#pragma unroll
                for (int rr = 0; rr < 4; ++rr)
                    v = (oo * 4 + rr == lane) ? acc[oo][rr] : v;
            const int o = lane >> 2;
            const int r = lane & 3;
            op[o * KSEL + g + r] = v;
        }
    }
}

// ---------------- fallback (fp32 table, R1 kernel) ----------------
#define FKPB 64
#define FKPW 16

__global__ __launch_bounds__(256) void ehead_f32_kernel(
    const float* __restrict__ h,
    const float* __restrict__ wt,
    const int*   __restrict__ index,
    float*       __restrict__ out)
{
    const int nkc = KSEL / FKPB;
    const int bl  = blockIdx.x / nkc;
    const int kc  = blockIdx.x % nkc;
    const int kbase = kc * FKPB;

    __shared__ float hs[OUTR * DIM];
    const float* hp = h + (size_t)bl * (OUTR * DIM);
    const int tid = threadIdx.x;
#pragma unroll
    for (int i = 0; i < (OUTR * DIM) / (256 * 4); ++i) {
        const int e = (i * 256 + tid) * 4;
        *(float4*)&hs[e] = *(const float4*)&hp[e];
    }
    __syncthreads();

    const int wave = tid >> 6;
    const int lane = tid & 63;
    const int* ip = index + (size_t)bl * KSEL + kbase + wave * FKPW;
    float*     op = out   + (size_t)bl * (OUTR * KSEL) + kbase + wave * FKPW;

    for (int g = 0; g < FKPW; g += 4) {
        const float4* r0 = (const float4*)(wt + (size_t)ip[g + 0] * DIM);
        const float4* r1 = (const float4*)(wt + (size_t)ip[g + 1] * DIM);
        const float4* r2 = (const float4*)(wt + (size_t)ip[g + 2] * DIM);
        const float4* r3 = (const float4*)(wt + (size_t)ip[g + 3] * DIM);
        float acc[OUTR][4];
#pragma unroll
        for (int o = 0; o < OUTR; ++o)
#pragma unroll
            for (int kk = 0; kk < 4; ++kk) acc[o][kk] = 0.f;
#pragma unroll
        for (int c = 0; c < DIM / 256; ++c) {
            const int off = c * 64 + lane;
            const float4 w0 = r0[off];
            const float4 w1 = r1[off];
            const float4 w2 = r2[off];
            const float4 w3 = r3[off];
#pragma unroll
            for (int o = 0; o < OUTR; ++o) {
                const float4 hv = *(const float4*)&hs[o * DIM + off * 4];
                acc[o][0] += hv.x * w0.x + hv.y * w0.y + hv.z * w0.z + hv.w * w0.w;
                acc[o][1] += hv.x * w1.x + hv.y * w1.y + hv.z * w1.z + hv.w * w1.w;
                acc[o][2] += hv.x * w2.x + hv.y * w2.y + hv.z * w2.z + hv.w * w2.w;
                acc[o][3] += hv.x * w3.x + hv.y * w3.y + hv.z * w3.z + hv.w * w3.w;
            }
        }
#pragma unroll
        for (int o = 0; o < OUTR; ++o)
#pragma unroll
            for (int kk = 0; kk < 4; ++kk) {
                float v = acc[o][kk];
#pragma unroll
                for (int s = 32; s >= 1; s >>= 1) v += __shfl_xor(v, s, 64);
                acc[o][kk] = v;
            }
        if (lane < 16) {
            float v = 0.f;
#pragma unroll
            for (int oo = 0; oo < OUTR; ++oo)
#pragma unroll
                for (int qq = 0; qq < 4; ++qq)
                    v = (oo * 4 + qq == lane) ? acc[oo][qq] : v;
            op[(lane >> 2) * KSEL + g + (lane & 3)] = v;
        }
    }
}

extern "C" void kernel_launch(void* const* d_in, const int* in_sizes, int n_in,
                              void* d_out, int out_size, void* d_ws, size_t ws_size,
                              hipStream_t stream) {
    const float* h   = (const float*)d_in[0];
    const float* wt  = (const float*)d_in[1];
    const int*   idx = (const int*)d_in[2];
    float*       out = (float*)d_out;

    if (ws_size >= WBF_BYTES) {
        ushort* wbf = (ushort*)d_ws;
        // convert W to bf16 table: 65.536M elems, 8/thread
        conv_kernel<<<(VOCAB * DIM) / (256 * 8), 256, 0, stream>>>(wt, wbf);
        const int grid = BATCH * LSEQ * NKC;   // 2200 blocks
        gather_bf16_kernel<<<grid, 256, 0, stream>>>(h, wbf, idx, out);
    } else {
        const int grid = BATCH * LSEQ * (KSEL / FKPB);
        ehead_f32_kernel<<<grid, 256, 0, stream>>>(h, wt, idx, out);
    }
}

// Round 3
// 518.442 us; speedup vs baseline: 1.1654x; 1.0630x over previous
//
#include <hip/hip_runtime.h>

#define BATCH 25
#define LSEQ  11
#define OUTR  4
#define DIM   2048
#define VOCAB 32000
#define KSEL  1024

typedef _Float16 half8  __attribute__((ext_vector_type(8)));
typedef float    floatx4 __attribute__((ext_vector_type(4)));

#define WH_BYTES ((size_t)VOCAB * DIM * 2)

// ---------------- W fp32 -> fp16 (RNE), nontemporal reads ----------------
// Reads stream past L3 (nt) so the fp16 table we WRITE stays L3-resident.
__global__ __launch_bounds__(256) void conv_f16(const float* __restrict__ w,
                                                _Float16* __restrict__ wh) {
    const size_t i = ((size_t)blockIdx.x * 256 + threadIdx.x) * 8;
    const floatx4 a = __builtin_nontemporal_load((const floatx4*)(w + i));
    const floatx4 b = __builtin_nontemporal_load((const floatx4*)(w + i + 4));
    half8 hv;
    hv[0] = (_Float16)a[0]; hv[1] = (_Float16)a[1];
    hv[2] = (_Float16)a[2]; hv[3] = (_Float16)a[3];
    hv[4] = (_Float16)b[0]; hv[5] = (_Float16)b[1];
    hv[6] = (_Float16)b[2]; hv[7] = (_Float16)b[3];
    *(half8*)(wh + i) = hv;
}

// ---------------- MFMA gather: out[bl,o,k] = h[bl,o,:] . Wh[idx[bl,k],:] ----
#define TPW 4                 // 16-wide k-tiles per wave
#define KPB (4 * TPW * 16)    // 256 k per block (4 waves)
#define NKC (KSEL / KPB)      // 4 blocks per (b,l)
#define ROWE 2080             // padded LDS row stride in fp16 elems (+64 B pad)

__global__ __launch_bounds__(256) void gather_mfma(
    const float*    __restrict__ h,
    const _Float16* __restrict__ wh,
    const int*      __restrict__ index,
    float*          __restrict__ out)
{
    __shared__ _Float16 hs[OUTR * ROWE];   // 16.25 KiB, padded rows

    const int bl   = blockIdx.x / NKC;
    const int kc   = blockIdx.x % NKC;
    const int tid  = threadIdx.x;
    const int wave = tid >> 6;
    const int lane = tid & 63;
    const int quad = lane >> 4;
    const int n    = lane & 15;            // MFMA column (k within tile)
    const int row  = lane & 3;             // A-row alias (M rows 4-15 duplicate 0-3)

    // ---- stage h[bl] (4x2048 fp32) into LDS as fp16, padded rows ----
    const float* hp = h + (size_t)bl * (OUTR * DIM);
#pragma unroll
    for (int o = 0; o < OUTR; ++o) {
        const int e = o * DIM + tid * 8;
        const floatx4 a = *(const floatx4*)(hp + e);
        const floatx4 b = *(const floatx4*)(hp + e + 4);
        half8 hv;
        hv[0] = (_Float16)a[0]; hv[1] = (_Float16)a[1];
        hv[2] = (_Float16)a[2]; hv[3] = (_Float16)a[3];
        hv[4] = (_Float16)b[0]; hv[5] = (_Float16)b[1];
        hv[6] = (_Float16)b[2]; hv[7] = (_Float16)b[3];
        *(half8*)(hs + o * ROWE + tid * 8) = hv;
    }
    __syncthreads();

    // ---- B row pointers: lane's column n -> gathered W row ----
    const int kb_blk = kc * KPB;
    const _Float16* bptr[TPW];
#pragma unroll
    for (int t = 0; t < TPW; ++t) {
        const int k_id = kb_blk + (wave * TPW + t) * 16 + n;
        const int ridx = index[(size_t)bl * KSEL + k_id];
        bptr[t] = wh + (size_t)ridx * DIM + quad * 8;
    }

    const _Float16* aptr = hs + row * ROWE + quad * 8;

    floatx4 acc[TPW];
#pragma unroll
    for (int t = 0; t < TPW; ++t) acc[t] = (floatx4){0.f, 0.f, 0.f, 0.f};

    // ---- K loop: 64 steps of K=32 ----
#pragma unroll 4
    for (int ks = 0; ks < DIM / 32; ++ks) {
        const half8 a = *(const half8*)(aptr + ks * 32);
        half8 b[TPW];
#pragma unroll
        for (int t = 0; t < TPW; ++t)
            b[t] = *(const half8*)(bptr[t] + ks * 32);
#pragma unroll
        for (int t = 0; t < TPW; ++t)
            acc[t] = __builtin_amdgcn_mfma_f32_16x16x32_f16(a, b[t], acc[t], 0, 0, 0);
    }

    // ---- epilogue: D rows 0-3 live in quad 0 (col=lane&15, row=reg) ----
    if (quad == 0) {
        float* op = out + (size_t)bl * (OUTR * KSEL) + kb_blk;
#pragma unroll
        for (int t = 0; t < TPW; ++t) {
            const int kcol = (wave * TPW + t) * 16 + n;
#pragma unroll
            for (int r = 0; r < OUTR; ++r)
                op[r * KSEL + kcol] = acc[t][r];
        }
    }
}

// ---------------- fallback (fp32 table) ----------------
#define FKPB 64
#define FKPW 16

__global__ __launch_bounds__(256) void ehead_f32_kernel(
    const float* __restrict__ h,
    const float* __restrict__ wt,
    const int*   __restrict__ index,
    float*       __restrict__ out)
{
    const int nkc = KSEL / FKPB;
    const int bl  = blockIdx.x / nkc;
    const int kc  = blockIdx.x % nkc;
    const int kbase = kc * FKPB;

    __shared__ float hsf[OUTR * DIM];
    const float* hp = h + (size_t)bl * (OUTR * DIM);
    const int tid = threadIdx.x;
#pragma unroll
    for (int i = 0; i < (OUTR * DIM) / (256 * 4); ++i) {
        const int e = (i * 256 + tid) * 4;
        *(float4*)&hsf[e] = *(const float4*)&hp[e];
    }
    __syncthreads();

    const int wave = tid >> 6;
    const int lane = tid & 63;
    const int* ip = index + (size_t)bl * KSEL + kbase + wave * FKPW;
    float*     op = out   + (size_t)bl * (OUTR * KSEL) + kbase + wave * FKPW;

    for (int g = 0; g < FKPW; g += 4) {
        const float4* r0 = (const float4*)(wt + (size_t)ip[g + 0] * DIM);
        const float4* r1 = (const float4*)(wt + (size_t)ip[g + 1] * DIM);
        const float4* r2 = (const float4*)(wt + (size_t)ip[g + 2] * DIM);
        const float4* r3 = (const float4*)(wt + (size_t)ip[g + 3] * DIM);
        float acc[OUTR][4];
#pragma unroll
        for (int o = 0; o < OUTR; ++o)
#pragma unroll
            for (int kk = 0; kk < 4; ++kk) acc[o][kk] = 0.f;
#pragma unroll
        for (int c = 0; c < DIM / 256; ++c) {
            const int off = c * 64 + lane;
            const float4 w0 = r0[off];
            const float4 w1 = r1[off];
            const float4 w2 = r2[off];
            const float4 w3 = r3[off];
#pragma unroll
            for (int o = 0; o < OUTR; ++o) {
                const float4 hv = *(const float4*)&hsf[o * DIM + off * 4];
                acc[o][0] += hv.x * w0.x + hv.y * w0.y + hv.z * w0.z + hv.w * w0.w;
                acc[o][1] += hv.x * w1.x + hv.y * w1.y + hv.z * w1.z + hv.w * w1.w;
                acc[o][2] += hv.x * w2.x + hv.y * w2.y + hv.z * w2.z + hv.w * w2.w;
                acc[o][3] += hv.x * w3.x + hv.y * w3.y + hv.z * w3.z + hv.w * w3.w;
            }
        }
#pragma unroll
        for (int o = 0; o < OUTR; ++o)
#pragma unroll
            for (int kk = 0; kk < 4; ++kk) {
                float v = acc[o][kk];
#pragma unroll
                for (int s = 32; s >= 1; s >>= 1) v += __shfl_xor(v, s, 64);
                acc[o][kk] = v;
            }
        if (lane < 16) {
            float v = 0.f;
#pragma unroll
            for (int oo = 0; oo < OUTR; ++oo)
#pragma unroll
                for (int qq = 0; qq < 4; ++qq)
                    v = (oo * 4 + qq == lane) ? acc[oo][qq] : v;
            op[(lane >> 2) * KSEL + g + (lane & 3)] = v;
        }
    }
}

extern "C" void kernel_launch(void* const* d_in, const int* in_sizes, int n_in,
                              void* d_out, int out_size, void* d_ws, size_t ws_size,
                              hipStream_t stream) {
    const float* h   = (const float*)d_in[0];
    const float* wt  = (const float*)d_in[1];
    const int*   idx = (const int*)d_in[2];
    float*       out = (float*)d_out;

    if (ws_size >= WH_BYTES) {
        _Float16* wh = (_Float16*)d_ws;
        conv_f16<<<(VOCAB * DIM) / (256 * 8), 256, 0, stream>>>(wt, wh);
        const int grid = BATCH * LSEQ * NKC;   // 1100 blocks, ~fully co-resident
        gather_mfma<<<grid, 256, 0, stream>>>(h, wh, idx, out);
    } else {
        const int grid = BATCH * LSEQ * (KSEL / FKPB);
        ehead_f32_kernel<<<grid, 256, 0, stream>>>(h, wt, idx, out);
    }
}